// Round 10
// baseline (888.946 us; speedup 1.0000x reference)
//
#include <hip/hip_runtime.h>

#define NN 50000
#define EE 800000
#define DD 128
#define DOUTC 64
#define TILES 4
#define TILEN 12500        // nodes per source tile; T slice = 3.2 MB -> fits XCD L2
#define SUBCAP 32          // slots per (node,tile); deg ~Poisson(4), P(>32) ~ 1e-17
#define BUCKET_BLKS 3125   // EE / 256
#define AGG_BLOCKS 1024
#define AGG_WAVES (AGG_BLOCKS * 4)   // 4096
#define NPW 13             // ceil(NN / AGG_WAVES)
#define CNT4_INTS (TILES * NN)
#define CNT4_ZBLKS 196     // ceil(CNT4_INTS*4 / 4096)

typedef unsigned int uint;
typedef unsigned short ushort;
typedef __attribute__((ext_vector_type(8))) short bf16x8;
typedef __attribute__((ext_vector_type(4))) float f32x4;

__device__ __forceinline__ float bf2f(uint b) { return __uint_as_float(b << 16); }
__device__ __forceinline__ ushort f2bf(float f) {
    uint u = __float_as_uint(f);
    u += 0x7fffu + ((u >> 16) & 1u);   // round-to-nearest-even
    return (ushort)(u >> 16);
}

// ---------------- k_pre: zero cnt4 + transpose-convert weights to bf16 [n][k] ----------
struct PreArgs {
    const float *w1, *w2, *w3, *wfc;
    ushort *wt1, *wt2, *wt3, *wtfc;
    int* cnt4;
};

__global__ __launch_bounds__(256) void k_pre(PreArgs a) {
    int b = blockIdx.x, t = threadIdx.x;
    if (b < CNT4_ZBLKS) {
        int i = (b * 256 + t) * 4;
        if (i < CNT4_INTS) *(int4*)(a.cnt4 + i) = (int4){0, 0, 0, 0};
    } else if (b < CNT4_ZBLKS + 192) {
        int b2 = b - CNT4_ZBLKS;
        const float* w = (b2 < 64) ? a.w1 : (b2 < 128) ? a.w2 : a.w3;
        ushort* wt = (b2 < 64) ? a.wt1 : (b2 < 128) ? a.wt2 : a.wt3;
        int idx = (b2 & 63) * 256 + t;         // idx = k*128 + n
        int k = idx >> 7, n = idx & 127;
        wt[n * DD + k] = f2bf(w[idx]);
    } else {
        int idx = (b - CNT4_ZBLKS - 192) * 256 + t;  // idx = k*64 + n
        int k = idx >> 6, n = idx & 63;
        a.wtfc[n * DD + k] = f2bf(a.wfc[idx]);
    }
}

// ---------------- k_bucket: edge scatter into (dst, src_tile) sub-lists ----------------
// colb row per node: 4 tiles x 32 slots x 2B = 256B. cnt4 layout [tile][node].
__global__ __launch_bounds__(256) void k_bucket(
    const int* __restrict__ src, const int* __restrict__ dst,
    int* __restrict__ cnt4, ushort* __restrict__ colb) {
    int e = blockIdx.x * 256 + threadIdx.x;    // EE == BUCKET_BLKS*256 exactly
    int d = dst[e];
    int s = src[e];
    int sub = s / TILEN;                       // 0..3 (compiler magic-div)
    int p = atomicAdd(&cnt4[sub * NN + d], 1);
    if (p < SUBCAP) colb[(size_t)d * 128 + sub * 32 + p] = (ushort)s;
}

__device__ __forceinline__ int tot_cnt(const int* __restrict__ cnt4, int n) {
    return cnt4[n] + cnt4[NN + n] + cnt4[2 * NN + n] + cnt4[3 * NN + n];
}

// ---------------- k_mm1: T[m,:] = bf16( dinv[m] * (x[m,:] @ W1) ), x fp32 ----------------
// D lane layout (16x16x32): col = lane&15 = m, row = quad*4 + reg = n.
__global__ __launch_bounds__(256) void k_mm1(
    const float* __restrict__ X, const ushort* __restrict__ WT,
    const int* __restrict__ cnt4, ushort* __restrict__ T) {
    const int wave = threadIdx.x >> 6;
    const int lane = threadIdx.x & 63;
    const int m0w = blockIdx.x * 64 + wave * 16;
    if (m0w >= NN) return;                     // NN % 16 == 0
    const int m = m0w + (lane & 15);
    const int quad = lane >> 4;
    f32x4 acc[8];
#pragma unroll
    for (int nt = 0; nt < 8; ++nt) acc[nt] = (f32x4){0.f, 0.f, 0.f, 0.f};
    const float* Hrow = X + (size_t)m * DD;
#pragma unroll
    for (int kk = 0; kk < 4; ++kk) {
        float4 a0 = *(const float4*)(Hrow + kk * 32 + quad * 8);
        float4 a1 = *(const float4*)(Hrow + kk * 32 + quad * 8 + 4);
        bf16x8 bfr;
        bfr[0] = (short)f2bf(a0.x); bfr[1] = (short)f2bf(a0.y);
        bfr[2] = (short)f2bf(a0.z); bfr[3] = (short)f2bf(a0.w);
        bfr[4] = (short)f2bf(a1.x); bfr[5] = (short)f2bf(a1.y);
        bfr[6] = (short)f2bf(a1.z); bfr[7] = (short)f2bf(a1.w);
#pragma unroll
        for (int nt = 0; nt < 8; ++nt) {
            bf16x8 afr = *(const bf16x8*)(WT + (size_t)(nt * 16 + (lane & 15)) * DD +
                                          kk * 32 + quad * 8);
            acc[nt] = __builtin_amdgcn_mfma_f32_16x16x32_bf16(afr, bfr, acc[nt], 0, 0, 0);
        }
    }
    float di = rsqrtf((float)(tot_cnt(cnt4, m) + 1));
#pragma unroll
    for (int nt = 0; nt < 8; ++nt) {
        int n = nt * 16 + quad * 4;
        uint2 o;
        o.x = (uint)f2bf(acc[nt][0] * di) | ((uint)f2bf(acc[nt][1] * di) << 16);
        o.y = (uint)f2bf(acc[nt][2] * di) | ((uint)f2bf(acc[nt][3] * di) << 16);
        *(uint2*)(T + (size_t)m * DD + n) = o;
    }
}

// ---------------- k_mm (layers 2,3): T = bf16( dinv * (A @ W) ), A bf16 ----------------
__global__ __launch_bounds__(256) void k_mm(
    const ushort* __restrict__ H, const ushort* __restrict__ WT,
    const int* __restrict__ cnt4, ushort* __restrict__ T) {
    const int wave = threadIdx.x >> 6;
    const int lane = threadIdx.x & 63;
    const int m0w = blockIdx.x * 64 + wave * 16;
    if (m0w >= NN) return;
    const int m = m0w + (lane & 15);
    const int quad = lane >> 4;
    f32x4 acc[8];
#pragma unroll
    for (int nt = 0; nt < 8; ++nt) acc[nt] = (f32x4){0.f, 0.f, 0.f, 0.f};
    const ushort* Hrow = H + (size_t)m * DD;
#pragma unroll
    for (int kk = 0; kk < 4; ++kk) {
        bf16x8 bfr = *(const bf16x8*)(Hrow + kk * 32 + quad * 8);
#pragma unroll
        for (int nt = 0; nt < 8; ++nt) {
            bf16x8 afr = *(const bf16x8*)(WT + (size_t)(nt * 16 + (lane & 15)) * DD +
                                          kk * 32 + quad * 8);
            acc[nt] = __builtin_amdgcn_mfma_f32_16x16x32_bf16(afr, bfr, acc[nt], 0, 0, 0);
        }
    }
    float di = rsqrtf((float)(tot_cnt(cnt4, m) + 1));
#pragma unroll
    for (int nt = 0; nt < 8; ++nt) {
        int n = nt * 16 + quad * 4;
        uint2 o;
        o.x = (uint)f2bf(acc[nt][0] * di) | ((uint)f2bf(acc[nt][1] * di) << 16);
        o.y = (uint)f2bf(acc[nt][2] * di) | ((uint)f2bf(acc[nt][3] * di) << 16);
        *(uint2*)(T + (size_t)m * DD + n) = o;
    }
}

// ---------------- k_agg: source-tiled gather-sum, register accumulators ----------------
// 1024 co-resident blocks; wave handles nodes W, W+4096, ... (NPW each, reg acc).
// Tile loop: all waves gather tile t's T slice (3.2 MB, L2-resident) before moving on.
__global__ __launch_bounds__(256) void k_agg(
    const ushort* __restrict__ T, const int* __restrict__ cnt4,
    const ushort* __restrict__ colb, const float* __restrict__ bias,
    ushort* __restrict__ A) {
    const int W = blockIdx.x * 4 + (threadIdx.x >> 6);
    const int lane = threadIdx.x & 63;
    const uint* Tv = (const uint*)T;
    float ax[NPW], ay[NPW];
#pragma unroll
    for (int i = 0; i < NPW; ++i) { ax[i] = 0.f; ay[i] = 0.f; }

    for (int t = 0; t < TILES; ++t) {
#pragma unroll
        for (int i = 0; i < NPW; ++i) {
            int n = W + i * AGG_WAVES;
            if (n < NN) {
                float sx = ax[i], sy = ay[i];
                if (n / TILEN == t) {                       // self-loop row lives in tile t
                    uint v = Tv[(size_t)n * 64 + lane];
                    sx += bf2f(v & 0xffffu); sy += bf2f(v >> 16);
                }
                int c = cnt4[t * NN + n];
                if (c > SUBCAP) c = SUBCAP;
                const ushort* bl = colb + (size_t)n * 128 + t * 32;
                int e = 0;
                for (; e + 7 < c; e += 8) {
                    uint vv[8];
#pragma unroll
                    for (int q = 0; q < 8; ++q) vv[q] = Tv[(size_t)bl[e + q] * 64 + lane];
#pragma unroll
                    for (int q = 0; q < 8; ++q) {
                        sx += bf2f(vv[q] & 0xffffu);
                        sy += bf2f(vv[q] >> 16);
                    }
                }
                for (; e < c; ++e) {
                    uint v = Tv[(size_t)bl[e] * 64 + lane];
                    sx += bf2f(v & 0xffffu);
                    sy += bf2f(v >> 16);
                }
                ax[i] = sx; ay[i] = sy;
            }
        }
    }
    float2 bv = ((const float2*)bias)[lane];
#pragma unroll
    for (int i = 0; i < NPW; ++i) {
        int n = W + i * AGG_WAVES;
        if (n < NN) {
            float di = rsqrtf((float)(tot_cnt(cnt4, n) + 1));
            float o0 = fmaxf(fmaf(ax[i], di, bv.x), 0.f);
            float o1 = fmaxf(fmaf(ay[i], di, bv.y), 0.f);
            ((uint*)A)[(size_t)n * 64 + lane] = (uint)f2bf(o0) | ((uint)f2bf(o1) << 16);
        }
    }
}

// ---------------- k_mm_final: out = A @ Wfc + bfc (fp32 out) ----------------
__global__ __launch_bounds__(256) void k_mm_final(
    const ushort* __restrict__ H, const ushort* __restrict__ WT,
    const float* __restrict__ bb, float* __restrict__ out) {
    const int wave = threadIdx.x >> 6;
    const int lane = threadIdx.x & 63;
    const int m0w = blockIdx.x * 64 + wave * 16;
    if (m0w >= NN) return;
    const int m = m0w + (lane & 15);
    const int quad = lane >> 4;
    f32x4 acc[4];
#pragma unroll
    for (int nt = 0; nt < 4; ++nt) acc[nt] = (f32x4){0.f, 0.f, 0.f, 0.f};
    const ushort* Hrow = H + (size_t)m * DD;
#pragma unroll
    for (int kk = 0; kk < 4; ++kk) {
        bf16x8 bfr = *(const bf16x8*)(Hrow + kk * 32 + quad * 8);
#pragma unroll
        for (int nt = 0; nt < 4; ++nt) {
            bf16x8 afr = *(const bf16x8*)(WT + (size_t)(nt * 16 + (lane & 15)) * DD +
                                          kk * 32 + quad * 8);
            acc[nt] = __builtin_amdgcn_mfma_f32_16x16x32_bf16(afr, bfr, acc[nt], 0, 0, 0);
        }
    }
#pragma unroll
    for (int nt = 0; nt < 4; ++nt) {
        int n = nt * 16 + quad * 4;
        float4 bvals = *(const float4*)(bb + n);
        float4 o = {acc[nt][0] + bvals.x, acc[nt][1] + bvals.y,
                    acc[nt][2] + bvals.z, acc[nt][3] + bvals.w};
        *(float4*)(out + (size_t)m * DOUTC + n) = o;
    }
}

// ---------------- launch ----------------
extern "C" void kernel_launch(void* const* d_in, const int* in_sizes, int n_in,
                              void* d_out, int out_size, void* d_ws, size_t ws_size,
                              hipStream_t stream) {
    const float* x   = (const float*)d_in[0];
    const int*   ei  = (const int*)d_in[1];
    const float* W1  = (const float*)d_in[2];
    const float* b1  = (const float*)d_in[3];
    const float* W2  = (const float*)d_in[4];
    const float* b2  = (const float*)d_in[5];
    const float* W3  = (const float*)d_in[6];
    const float* b3  = (const float*)d_in[7];
    const float* Wfc = (const float*)d_in[8];
    const float* bfc = (const float*)d_in[9];

    char* ws = (char*)d_ws;
    size_t off = 0;
    auto take = [&](size_t bytes) {
        void* p = ws + off;
        off = (off + bytes + 255) & ~(size_t)255;
        return p;
    };
    int*    cnt4 = (int*)take((size_t)CNT4_INTS * 4);      // 800 KB [tile][node]
    ushort* colb = (ushort*)take((size_t)NN * 256);        // 12.8 MB (4 tiles x 32 slots)
    ushort* T    = (ushort*)take((size_t)NN * DD * 2);     // 12.8 MB
    ushort* A    = (ushort*)take((size_t)NN * DD * 2);     // 12.8 MB
    ushort* WT1  = (ushort*)take((size_t)DD * DD * 2);
    ushort* WT2  = (ushort*)take((size_t)DD * DD * 2);
    ushort* WT3  = (ushort*)take((size_t)DD * DD * 2);
    ushort* WTfc = (ushort*)take((size_t)DOUTC * DD * 2);

    const int* src = ei;
    const int* dst = ei + EE;

    PreArgs pa;
    pa.w1 = W1; pa.w2 = W2; pa.w3 = W3; pa.wfc = Wfc;
    pa.wt1 = WT1; pa.wt2 = WT2; pa.wt3 = WT3; pa.wtfc = WTfc;
    pa.cnt4 = cnt4;
    k_pre<<<CNT4_ZBLKS + 192 + 32, 256, 0, stream>>>(pa);

    const int mm_grid = (NN + 63) / 64;   // 782

    k_bucket<<<BUCKET_BLKS, 256, 0, stream>>>(src, dst, cnt4, colb);
    k_mm1<<<mm_grid, 256, 0, stream>>>(x, WT1, cnt4, T);
    k_agg<<<AGG_BLOCKS, 256, 0, stream>>>(T, cnt4, colb, b1, A);
    k_mm<<<mm_grid, 256, 0, stream>>>(A, WT2, cnt4, T);
    k_agg<<<AGG_BLOCKS, 256, 0, stream>>>(T, cnt4, colb, b2, A);
    k_mm<<<mm_grid, 256, 0, stream>>>(A, WT3, cnt4, T);
    k_agg<<<AGG_BLOCKS, 256, 0, stream>>>(T, cnt4, colb, b3, A);
    k_mm_final<<<mm_grid, 256, 0, stream>>>(A, WTfc, bfc, (float*)d_out);
}

// Round 12
// 335.944 us; speedup vs baseline: 2.6461x; 2.6461x over previous
//
#include <hip/hip_runtime.h>

#define NN 50000
#define EE 800000
#define DD 128
#define DOUTC 64
#define CAP 64            // slots per node; degree ~Poisson(16), P(>64) negligible
#define BUCKET_BLKS 3125  // EE / 256
#define CNT_ZBLKS 196     // ceil(NN / 256)

typedef unsigned int uint;
typedef unsigned short ushort;
typedef __attribute__((ext_vector_type(8))) short bf16x8;
typedef __attribute__((ext_vector_type(4))) float f32x4;
typedef __attribute__((ext_vector_type(4))) uint u32x4;

__device__ __forceinline__ float bf2f(uint b) { return __uint_as_float(b << 16); }
__device__ __forceinline__ ushort f2bf(float f) {
    uint u = __float_as_uint(f);
    u += 0x7fffu + ((u >> 16) & 1u);   // round-to-nearest-even
    return (ushort)(u >> 16);
}

// ---------------- k_pre: zero cnt + transpose-convert weights to bf16 [n][k] ----------
struct PreArgs {
    const float *w1, *w2, *w3, *wfc;
    ushort *wt1, *wt2, *wt3, *wtfc;
    int* cnt;
};

__global__ __launch_bounds__(256) void k_pre(PreArgs a) {
    int b = blockIdx.x, t = threadIdx.x;
    if (b < CNT_ZBLKS) {
        int i = b * 256 + t;
        if (i < NN) a.cnt[i] = 0;
    } else if (b < CNT_ZBLKS + 192) {
        int b2 = b - CNT_ZBLKS;
        const float* w = (b2 < 64) ? a.w1 : (b2 < 128) ? a.w2 : a.w3;
        ushort* wt = (b2 < 64) ? a.wt1 : (b2 < 128) ? a.wt2 : a.wt3;
        int idx = (b2 & 63) * 256 + t;         // idx = k*128 + n
        int k = idx >> 7, n = idx & 127;
        wt[n * DD + k] = f2bf(w[idx]);
    } else {
        int idx = (b - CNT_ZBLKS - 192) * 256 + t;  // idx = k*64 + n
        int k = idx >> 6, n = idx & 63;
        a.wtfc[n * DD + k] = f2bf(a.wfc[idx]);
    }
}

// ---------------- k_bucket: edge scatter (nt edge reads) ----------------
// colb: 64 ushort slots per node (128B, 16-aligned); cnt separate (stays hot in L2).
__global__ __launch_bounds__(256) void k_bucket(
    const int* __restrict__ src, const int* __restrict__ dst,
    int* __restrict__ cnt, ushort* __restrict__ colb) {
    int e = blockIdx.x * 256 + threadIdx.x;    // EE == BUCKET_BLKS*256 exactly
    int d = __builtin_nontemporal_load(dst + e);
    int s = __builtin_nontemporal_load(src + e);
    int p = atomicAdd(&cnt[d], 1);
    if (p < CAP) colb[((size_t)d << 6) + p] = (ushort)s;
}

// ---------------- k_mm1: T[m,:] = bf16( dinv[m] * (x[m,:] @ W1) ), x fp32 ----------------
// D lane layout (16x16x32): col = lane&15 = m, row = quad*4 + reg = n.
__global__ __launch_bounds__(256) void k_mm1(
    const float* __restrict__ X, const ushort* __restrict__ WT,
    const int* __restrict__ cnt, ushort* __restrict__ T) {
    const int wave = threadIdx.x >> 6;
    const int lane = threadIdx.x & 63;
    const int m0w = blockIdx.x * 64 + wave * 16;
    if (m0w >= NN) return;                     // NN % 16 == 0
    const int m = m0w + (lane & 15);
    const int quad = lane >> 4;
    f32x4 acc[8];
#pragma unroll
    for (int nt = 0; nt < 8; ++nt) acc[nt] = (f32x4){0.f, 0.f, 0.f, 0.f};
    const float* Hrow = X + (size_t)m * DD;
#pragma unroll
    for (int kk = 0; kk < 4; ++kk) {
        f32x4 a0 = __builtin_nontemporal_load((const f32x4*)(Hrow + kk * 32 + quad * 8));
        f32x4 a1 = __builtin_nontemporal_load((const f32x4*)(Hrow + kk * 32 + quad * 8 + 4));
        bf16x8 bfr;
        bfr[0] = (short)f2bf(a0[0]); bfr[1] = (short)f2bf(a0[1]);
        bfr[2] = (short)f2bf(a0[2]); bfr[3] = (short)f2bf(a0[3]);
        bfr[4] = (short)f2bf(a1[0]); bfr[5] = (short)f2bf(a1[1]);
        bfr[6] = (short)f2bf(a1[2]); bfr[7] = (short)f2bf(a1[3]);
#pragma unroll
        for (int nt = 0; nt < 8; ++nt) {
            bf16x8 afr = *(const bf16x8*)(WT + (size_t)(nt * 16 + (lane & 15)) * DD +
                                          kk * 32 + quad * 8);
            acc[nt] = __builtin_amdgcn_mfma_f32_16x16x32_bf16(afr, bfr, acc[nt], 0, 0, 0);
        }
    }
    float di = rsqrtf((float)(cnt[m] + 1));
#pragma unroll
    for (int nt = 0; nt < 8; ++nt) {
        int n = nt * 16 + quad * 4;
        uint2 o;
        o.x = (uint)f2bf(acc[nt][0] * di) | ((uint)f2bf(acc[nt][1] * di) << 16);
        o.y = (uint)f2bf(acc[nt][2] * di) | ((uint)f2bf(acc[nt][3] * di) << 16);
        *(uint2*)(T + (size_t)m * DD + n) = o;   // cached: agg reads it next
    }
}

// ---------------- k_mm (layers 2,3): T = bf16( dinv * (A @ W) ), A bf16 (nt reads) ------
__global__ __launch_bounds__(256) void k_mm(
    const ushort* __restrict__ H, const ushort* __restrict__ WT,
    const int* __restrict__ cnt, ushort* __restrict__ T) {
    const int wave = threadIdx.x >> 6;
    const int lane = threadIdx.x & 63;
    const int m0w = blockIdx.x * 64 + wave * 16;
    if (m0w >= NN) return;
    const int m = m0w + (lane & 15);
    const int quad = lane >> 4;
    f32x4 acc[8];
#pragma unroll
    for (int nt = 0; nt < 8; ++nt) acc[nt] = (f32x4){0.f, 0.f, 0.f, 0.f};
    const ushort* Hrow = H + (size_t)m * DD;
#pragma unroll
    for (int kk = 0; kk < 4; ++kk) {
        bf16x8 bfr = __builtin_nontemporal_load(
            (const bf16x8*)(Hrow + kk * 32 + quad * 8));
#pragma unroll
        for (int nt = 0; nt < 8; ++nt) {
            bf16x8 afr = *(const bf16x8*)(WT + (size_t)(nt * 16 + (lane & 15)) * DD +
                                          kk * 32 + quad * 8);
            acc[nt] = __builtin_amdgcn_mfma_f32_16x16x32_bf16(afr, bfr, acc[nt], 0, 0, 0);
        }
    }
    float di = rsqrtf((float)(cnt[m] + 1));
#pragma unroll
    for (int nt = 0; nt < 8; ++nt) {
        int n = nt * 16 + quad * 4;
        uint2 o;
        o.x = (uint)f2bf(acc[nt][0] * di) | ((uint)f2bf(acc[nt][1] * di) << 16);
        o.y = (uint)f2bf(acc[nt][2] * di) | ((uint)f2bf(acc[nt][3] * di) << 16);
        *(uint2*)(T + (size_t)m * DD + n) = o;
    }
}

// ---------------- k_agg: A[i,:] = bf16(relu(di * (T'[i,:] + sum_j T'[j,:]) + b)) --------
// One wave/node. Slot list read as nt u32x4 (stream, don't pollute L2); T gathers cached.
__global__ __launch_bounds__(256) void k_agg(
    const ushort* __restrict__ T, const int* __restrict__ cnt,
    const ushort* __restrict__ colb, const float* __restrict__ bias,
    ushort* __restrict__ A) {
    int node = blockIdx.x * 4 + (threadIdx.x >> 6);
    if (node >= NN) return;
    int lane = threadIdx.x & 63;
    const uint* Tv = (const uint*)T;
    size_t base = (size_t)node * 64;
    int c = cnt[node];
    int end = c < CAP ? c : CAP;
    uint w0 = Tv[base + lane];                       // self-loop (pre-scaled)
    float ax = bf2f(w0 & 0xffffu), ay = bf2f(w0 >> 16);
    const u32x4* bl4 = (const u32x4*)(colb + ((size_t)node << 6));
    for (int e0 = 0; e0 < end; e0 += 8) {
        u32x4 w = __builtin_nontemporal_load(bl4 + (e0 >> 3));
        uint s[8] = {w[0] & 0xffffu, w[0] >> 16, w[1] & 0xffffu, w[1] >> 16,
                     w[2] & 0xffffu, w[2] >> 16, w[3] & 0xffffu, w[3] >> 16};
        if (e0 + 8 <= end) {
            uint vv[8];
#pragma unroll
            for (int q = 0; q < 8; ++q) vv[q] = Tv[(size_t)s[q] * 64 + lane];
#pragma unroll
            for (int q = 0; q < 8; ++q) {
                ax += bf2f(vv[q] & 0xffffu);
                ay += bf2f(vv[q] >> 16);
            }
        } else {
#pragma unroll
            for (int q = 0; q < 8; ++q) {
                if (e0 + q < end) {                  // wave-uniform branch
                    uint v = Tv[(size_t)s[q] * 64 + lane];
                    ax += bf2f(v & 0xffffu);
                    ay += bf2f(v >> 16);
                }
            }
        }
    }
    float di = rsqrtf((float)(c + 1));
    float2 bv = ((const float2*)bias)[lane];
    float o0 = fmaxf(fmaf(ax, di, bv.x), 0.f);
    float o1 = fmaxf(fmaf(ay, di, bv.y), 0.f);
    __builtin_nontemporal_store((uint)f2bf(o0) | ((uint)f2bf(o1) << 16),
                                (uint*)A + base + lane);
}

// ---------------- k_mm_final: out = A @ Wfc + bfc (fp32 out, nt) ----------------
__global__ __launch_bounds__(256) void k_mm_final(
    const ushort* __restrict__ H, const ushort* __restrict__ WT,
    const float* __restrict__ bb, float* __restrict__ out) {
    const int wave = threadIdx.x >> 6;
    const int lane = threadIdx.x & 63;
    const int m0w = blockIdx.x * 64 + wave * 16;
    if (m0w >= NN) return;
    const int m = m0w + (lane & 15);
    const int quad = lane >> 4;
    f32x4 acc[4];
#pragma unroll
    for (int nt = 0; nt < 4; ++nt) acc[nt] = (f32x4){0.f, 0.f, 0.f, 0.f};
    const ushort* Hrow = H + (size_t)m * DD;
#pragma unroll
    for (int kk = 0; kk < 4; ++kk) {
        bf16x8 bfr = __builtin_nontemporal_load(
            (const bf16x8*)(Hrow + kk * 32 + quad * 8));
#pragma unroll
        for (int nt = 0; nt < 4; ++nt) {
            bf16x8 afr = *(const bf16x8*)(WT + (size_t)(nt * 16 + (lane & 15)) * DD +
                                          kk * 32 + quad * 8);
            acc[nt] = __builtin_amdgcn_mfma_f32_16x16x32_bf16(afr, bfr, acc[nt], 0, 0, 0);
        }
    }
#pragma unroll
    for (int nt = 0; nt < 4; ++nt) {
        int n = nt * 16 + quad * 4;
        float4 bvals = *(const float4*)(bb + n);
        f32x4 o = {acc[nt][0] + bvals.x, acc[nt][1] + bvals.y,
                   acc[nt][2] + bvals.z, acc[nt][3] + bvals.w};
        __builtin_nontemporal_store(o, (f32x4*)(out + (size_t)m * DOUTC + n));
    }
}

// ---------------- launch ----------------
extern "C" void kernel_launch(void* const* d_in, const int* in_sizes, int n_in,
                              void* d_out, int out_size, void* d_ws, size_t ws_size,
                              hipStream_t stream) {
    const float* x   = (const float*)d_in[0];
    const int*   ei  = (const int*)d_in[1];
    const float* W1  = (const float*)d_in[2];
    const float* b1  = (const float*)d_in[3];
    const float* W2  = (const float*)d_in[4];
    const float* b2  = (const float*)d_in[5];
    const float* W3  = (const float*)d_in[6];
    const float* b3  = (const float*)d_in[7];
    const float* Wfc = (const float*)d_in[8];
    const float* bfc = (const float*)d_in[9];

    char* ws = (char*)d_ws;
    size_t off = 0;
    auto take = [&](size_t bytes) {
        void* p = ws + off;
        off = (off + bytes + 255) & ~(size_t)255;
        return p;
    };
    int*    cnt  = (int*)take((size_t)NN * 4);             // 200 KB
    ushort* colb = (ushort*)take((size_t)NN * CAP * 2);    // 6.4 MB, 16B-aligned rows
    ushort* T    = (ushort*)take((size_t)NN * DD * 2);     // 12.8 MB
    ushort* A    = (ushort*)take((size_t)NN * DD * 2);     // 12.8 MB
    ushort* WT1  = (ushort*)take((size_t)DD * DD * 2);
    ushort* WT2  = (ushort*)take((size_t)DD * DD * 2);
    ushort* WT3  = (ushort*)take((size_t)DD * DD * 2);
    ushort* WTfc = (ushort*)take((size_t)DOUTC * DD * 2);

    const int* src = ei;
    const int* dst = ei + EE;

    PreArgs pa;
    pa.w1 = W1; pa.w2 = W2; pa.w3 = W3; pa.wfc = Wfc;
    pa.wt1 = WT1; pa.wt2 = WT2; pa.wt3 = WT3; pa.wtfc = WTfc;
    pa.cnt = cnt;
    k_pre<<<CNT_ZBLKS + 192 + 32, 256, 0, stream>>>(pa);

    const int mm_grid  = (NN + 63) / 64;   // 782
    const int agg_grid = (NN + 3) / 4;     // 12500

    k_bucket<<<BUCKET_BLKS, 256, 0, stream>>>(src, dst, cnt, colb);
    k_mm1<<<mm_grid, 256, 0, stream>>>(x, WT1, cnt, T);
    k_agg<<<agg_grid, 256, 0, stream>>>(T, cnt, colb, b1, A);
    k_mm<<<mm_grid, 256, 0, stream>>>(A, WT2, cnt, T);
    k_agg<<<agg_grid, 256, 0, stream>>>(T, cnt, colb, b2, A);
    k_mm<<<mm_grid, 256, 0, stream>>>(A, WT3, cnt, T);
    k_agg<<<agg_grid, 256, 0, stream>>>(T, cnt, colb, b3, A);
    k_mm_final<<<mm_grid, 256, 0, stream>>>(A, WTfc, bfc, (float*)d_out);
}